// Round 1
// baseline (3231.120 us; speedup 1.0000x reference)
//
#include <hip/hip_runtime.h>

#define NTOK 49
#define DIMC 384
#define NH 12
#define HD 32
#define NWM 64
#define SCALE 0.17677669529663687f  // 1/sqrt(32)

typedef __attribute__((ext_vector_type(8))) __bf16 bf16x8;
typedef __attribute__((ext_vector_type(4))) float f32x4;

__device__ __forceinline__ unsigned short f2b(float f) {
  union { float f; unsigned u; } v; v.f = f;
  unsigned r = v.u + 0x7fffu + ((v.u >> 16) & 1u);  // round-to-nearest-even
  return (unsigned short)(r >> 16);
}

// ---------------- prep: weight transpose->bf16, bias gather ----------------
__global__ void prep_kernel(const float* __restrict__ qkv_w,
                            const float* __restrict__ out_w,
                            const float* __restrict__ table,
                            const int* __restrict__ rel_index,
                            unsigned short* __restrict__ wtq,   // [1152][384] bf16
                            unsigned short* __restrict__ wto,   // [384][384]  bf16
                            float* __restrict__ biasM) {        // [12][49][49] f32
  int id = blockIdx.x * 256 + threadIdx.x;
  if (id < 1152 * 384) {
    int col = id / 384, k = id - col * 384;
    wtq[id] = f2b(qkv_w[k * 1152 + col]);
  } else if (id < 1152 * 384 + 384 * 384) {
    int id2 = id - 1152 * 384;
    int col = id2 / 384, k = id2 - col * 384;
    wto[id2] = f2b(out_w[k * 384 + col]);
  } else if (id < 1152 * 384 + 384 * 384 + NH * NTOK * NTOK) {
    int id3 = id - (1152 * 384 + 384 * 384);
    int h = id3 / (NTOK * NTOK), ij = id3 - h * (NTOK * NTOK);
    biasM[id3] = table[rel_index[ij] * NH + h];
  }
}

// ---------------- fused qkv + attention, one block per window ----------------
// LDS map (ushort elements):
//  xs  @     0  : [49][392]  x window bf16            (38416 B)
//  qs  @ 19208  : [49][40]   q (pre-scaled) bf16      ( 3920 B)
//  ks  @ 21168  : [49][40]   k bf16                   ( 3920 B)
//  vt  @ 23128  : [32][72]   v transposed bf16        ( 4608 B)
//  S   @ 25432  : [49][52]   f32 scores + row scratch (10192 B)
//  Pb = qs (overlay): [49][72] bf16 exp(S) for PV     ( 7056 B, fits qs+ks)
// total 61056 B -> 2 blocks/CU
__global__ __launch_bounds__(256, 2) void attn_kernel(
    const float* __restrict__ x, const float* __restrict__ mask,
    const unsigned short* __restrict__ wtq, const float* __restrict__ qkv_b,
    const float* __restrict__ biasM, float* __restrict__ out) {
  __shared__ __align__(16) unsigned short smem[30528];
  unsigned short* xs = smem;
  unsigned short* qs = smem + 19208;
  unsigned short* ks = smem + 21168;
  unsigned short* vt = smem + 23128;
  float* S = (float*)(smem + 25432);
  unsigned short* Pb = qs;

  const int tid = threadIdx.x;
  const int lane = tid & 63;
  const int wv = tid >> 6;      // wave = M-tile
  const int quad = lane >> 4;
  const int l16 = lane & 15;
  const int b = blockIdx.x;

  // stage x window -> bf16 LDS
  const float* xw = x + (size_t)b * (NTOK * DIMC);
  for (int t = tid; t < NTOK * 96; t += 256) {
    int i = t / 96, k4 = (t - (t / 96) * 96) * 4;
    float4 v = *(const float4*)(xw + i * DIMC + k4);
    ushort4 bb;
    bb.x = f2b(v.x); bb.y = f2b(v.y); bb.z = f2b(v.z); bb.w = f2b(v.w);
    *(ushort4*)(xs + i * 392 + k4) = bb;
  }
  __syncthreads();

  const float* maskw = mask + (size_t)(b & (NWM - 1)) * (NTOK * NTOK);
  float* outw = out + (size_t)b * (NTOK * DIMC);

  for (int h = 0; h < NH; ++h) {
    // ---- P1: qkv slice for head h: [49(pad64) x 96] = xs[49x384] @ W[384x96]
    f32x4 acc[6];
#pragma unroll
    for (int nt = 0; nt < 6; ++nt) acc[nt] = (f32x4){0.f, 0.f, 0.f, 0.f};
    {
      const unsigned short* apt = xs + (wv * 16 + l16) * 392 + quad * 8;
      for (int kt = 0; kt < 12; ++kt) {
        bf16x8 a = *(const bf16x8*)(apt + kt * 32);
#pragma unroll
        for (int nt = 0; nt < 6; ++nt) {
          int c = nt * 16 + l16;
          int gcol = (c >> 5) * DIMC + h * HD + (c & 31);  // col in [0,1152)
          bf16x8 bb = *(const bf16x8*)(wtq + (size_t)gcol * 384 + kt * 32 + quad * 8);
          acc[nt] = __builtin_amdgcn_mfma_f32_16x16x32_bf16(a, bb, acc[nt], 0, 0, 0);
        }
      }
    }
    // zero v^T pad tokens 49..63 (so PV K-padding contributes 0)
    for (int t = tid; t < 32 * 15; t += 256) {
      int d = t / 15, i2 = 49 + (t - (t / 15) * 15);
      vt[d * 72 + i2] = 0;
    }
    // epilogue: +bias, write q(scaled)/k/v^T as bf16
#pragma unroll
    for (int nt = 0; nt < 6; ++nt) {
      int c = nt * 16 + l16;
      int s = c >> 5, d = c & 31;  // s uniform per nt
      float bias = qkv_b[s * DIMC + h * HD + d];
#pragma unroll
      for (int r = 0; r < 4; ++r) {
        int i = wv * 16 + quad * 4 + r;
        if (i < NTOK) {
          float val = acc[nt][r] + bias;
          if (s == 0)      qs[i * 40 + d] = f2b(val * SCALE);
          else if (s == 1) ks[i * 40 + d] = f2b(val);
          else             vt[d * 72 + i] = f2b(val);
        }
      }
    }
    __syncthreads();

    // ---- P2: S = q k^T + relbias + mask  (K=32 exactly: one MFMA/tile)
    {
      f32x4 sacc[4];
#pragma unroll
      for (int nt = 0; nt < 4; ++nt) sacc[nt] = (f32x4){0.f, 0.f, 0.f, 0.f};
      bf16x8 a = *(const bf16x8*)(qs + (wv * 16 + l16) * 40 + quad * 8);
#pragma unroll
      for (int nt = 0; nt < 4; ++nt) {
        bf16x8 bk = *(const bf16x8*)(ks + (nt * 16 + l16) * 40 + quad * 8);
        sacc[nt] = __builtin_amdgcn_mfma_f32_16x16x32_bf16(a, bk, sacc[nt], 0, 0, 0);
      }
      const float* bM = biasM + h * (NTOK * NTOK);
#pragma unroll
      for (int nt = 0; nt < 4; ++nt) {
        int j = nt * 16 + l16;
        if (j < NTOK) {
#pragma unroll
          for (int r = 0; r < 4; ++r) {
            int i = wv * 16 + quad * 4 + r;
            if (i < NTOK)
              S[i * 52 + j] = sacc[nt][r] + bM[i * NTOK + j] + maskw[i * NTOK + j];
          }
        }
      }
    }
    __syncthreads();

    // ---- softmax over rows (49x49), 3 threads per row ----
    if (tid < 147) {
      int rr = tid / 3, ss = tid - (tid / 3) * 3;
      float mx = -1e30f;
      for (int j = ss; j < NTOK; j += 3) mx = fmaxf(mx, S[rr * 52 + j]);
      S[rr * 52 + 49 + ss] = mx;
    }
    __syncthreads();
    if (tid < NTOK) {
      float mx = fmaxf(S[tid * 52 + 49], fmaxf(S[tid * 52 + 50], S[tid * 52 + 51]));
      S[tid * 52 + 49] = mx;
    }
    __syncthreads();
    if (tid < 147) {
      int rr = tid / 3, ss = tid - (tid / 3) * 3;
      float mx = S[rr * 52 + 49];
      float sum = 0.f;
      for (int j = ss; j < NTOK; j += 3) {
        float e = __expf(S[rr * 52 + j] - mx);
        Pb[rr * 72 + j] = f2b(e);   // unnormalized P, bf16 (overlays dead q/k)
        sum += e;
      }
      S[rr * 52 + ss] = sum;        // own column, read-before-write within thread
      for (int j = 49 + ss; j < 64; j += 3) Pb[rr * 72 + j] = 0;  // K-pad zeros
    }
    __syncthreads();
    if (tid < NTOK) {
      float tot = S[tid * 52 + 0] + S[tid * 52 + 1] + S[tid * 52 + 2];
      S[tid * 52 + 49] = 1.0f / tot;  // row inv-sum (max no longer needed)
    }
    __syncthreads();

    // ---- P3: O = P V  (K = 49 padded to 64; pads zeroed above) ----
    {
      f32x4 oacc[2];
      oacc[0] = (f32x4){0.f, 0.f, 0.f, 0.f};
      oacc[1] = (f32x4){0.f, 0.f, 0.f, 0.f};
#pragma unroll
      for (int k0 = 0; k0 < 64; k0 += 32) {
        bf16x8 a = *(const bf16x8*)(Pb + (wv * 16 + l16) * 72 + k0 + quad * 8);
#pragma unroll
        for (int nt = 0; nt < 2; ++nt) {
          bf16x8 bv = *(const bf16x8*)(vt + (nt * 16 + l16) * 72 + k0 + quad * 8);
          oacc[nt] = __builtin_amdgcn_mfma_f32_16x16x32_bf16(a, bv, oacc[nt], 0, 0, 0);
        }
      }
#pragma unroll
      for (int nt = 0; nt < 2; ++nt) {
        int d = nt * 16 + l16;
#pragma unroll
        for (int r = 0; r < 4; ++r) {
          int i = wv * 16 + quad * 4 + r;
          if (i < NTOK)
            outw[i * DIMC + h * HD + d] = oacc[nt][r] * S[i * 52 + 49];
        }
      }
    }
    __syncthreads();  // protect qs/ks/vt/S reuse next head
  }
}

// ---------------- out projection, in-place on d_out, 64 rows/block ----------
__global__ __launch_bounds__(256, 2) void proj_kernel(
    float* __restrict__ io, const unsigned short* __restrict__ wto,
    const float* __restrict__ out_b) {
  __shared__ __align__(16) unsigned short as[64 * 392];  // 50176 B
  const int tid = threadIdx.x;
  const int lane = tid & 63, wv = tid >> 6, quad = lane >> 4, l16 = lane & 15;
  float* base = io + (size_t)blockIdx.x * (64 * DIMC);
  for (int t = tid; t < 64 * 96; t += 256) {
    int i = t / 96, k4 = (t - (t / 96) * 96) * 4;
    float4 v = *(const float4*)(base + i * DIMC + k4);
    ushort4 bb;
    bb.x = f2b(v.x); bb.y = f2b(v.y); bb.z = f2b(v.z); bb.w = f2b(v.w);
    *(ushort4*)(as + i * 392 + k4) = bb;
  }
  __syncthreads();  // all rows staged before any in-place overwrite
  f32x4 acc[24];
#pragma unroll
  for (int nt = 0; nt < 24; ++nt) acc[nt] = (f32x4){0.f, 0.f, 0.f, 0.f};
  const unsigned short* apt = as + (wv * 16 + l16) * 392 + quad * 8;
  for (int kt = 0; kt < 12; ++kt) {
    bf16x8 a = *(const bf16x8*)(apt + kt * 32);
#pragma unroll
    for (int nt = 0; nt < 24; ++nt) {
      bf16x8 bb = *(const bf16x8*)(wto + (size_t)(nt * 16 + l16) * 384 + kt * 32 + quad * 8);
      acc[nt] = __builtin_amdgcn_mfma_f32_16x16x32_bf16(a, bb, acc[nt], 0, 0, 0);
    }
  }
#pragma unroll
  for (int nt = 0; nt < 24; ++nt) {
    int c = nt * 16 + l16;
    float bias = out_b[c];
#pragma unroll
    for (int r = 0; r < 4; ++r) {
      int i = wv * 16 + quad * 4 + r;
      base[i * DIMC + c] = acc[nt][r] + bias;
    }
  }
}

extern "C" void kernel_launch(void* const* d_in, const int* in_sizes, int n_in,
                              void* d_out, int out_size, void* d_ws, size_t ws_size,
                              hipStream_t stream) {
  (void)n_in; (void)out_size; (void)ws_size;
  const float* x       = (const float*)d_in[0];
  const float* mask    = (const float*)d_in[1];
  const float* qkv_w   = (const float*)d_in[2];
  const float* qkv_b   = (const float*)d_in[3];
  const float* table   = (const float*)d_in[4];
  const int*   rel_idx = (const int*)d_in[5];
  const float* out_w   = (const float*)d_in[6];
  const float* out_b   = (const float*)d_in[7];
  float* out = (float*)d_out;

  // workspace: WTq bf16 [1152*384] | WTo bf16 [384*384] | biasM f32 [12*49*49]
  unsigned short* wtq = (unsigned short*)d_ws;
  unsigned short* wto = wtq + 1152 * 384;
  float* biasM = (float*)(wto + 384 * 384);

  const int B = in_sizes[0] / (NTOK * DIMC);  // 4096
  const int prep_total = 1152 * 384 + 384 * 384 + NH * NTOK * NTOK;
  prep_kernel<<<(prep_total + 255) / 256, 256, 0, stream>>>(
      qkv_w, out_w, table, rel_idx, wtq, wto, biasM);
  attn_kernel<<<B, 256, 0, stream>>>(x, mask, wtq, qkv_b, biasM, out);
  proj_kernel<<<(B * NTOK) / 64, 256, 0, stream>>>(out, wto, out_b);
}